// Round 18
// baseline (337.904 us; speedup 1.0000x reference)
//
#include <hip/hip_runtime.h>
#include <hip/hip_bf16.h>
#include <math.h>

static __device__ __forceinline__ float lrelu(float v){ return v > 0.0f ? v : 0.01f*v; }

static __device__ __forceinline__ unsigned short f2bf(float f){
  unsigned int u = __float_as_uint(f);
  unsigned int r = (u + 0x7fffu + ((u >> 16) & 1u)) >> 16;
  return (unsigned short)r;
}
static __device__ __forceinline__ float bf2f(unsigned short u){
  return __uint_as_float(((unsigned int)u) << 16);
}
static __device__ __forceinline__ unsigned int pack_bf2(float lo, float hi){
  __hip_bfloat162 bb = __float22bfloat162_rn(make_float2(lo, hi));
  return *reinterpret_cast<unsigned int*>(&bb);
}
static __device__ __forceinline__ void gload16(const void* g, void* l){
  __builtin_amdgcn_global_load_lds(
    (const __attribute__((address_space(1))) void*)(const void*)g,
    (__attribute__((address_space(3))) void*)l, 16, 0, 0);
}

// XCD-aware bijective block swizzle (T1, m204 formula): each XCD gets a
// contiguous logical chunk, logical order is N-tile-fastest so blocks sharing
// an A-panel land on the same XCD's L2.
static __device__ __forceinline__ void xcd_tiles(int &bmt, int &bnt){
  int nwg  = gridDim.x * gridDim.y;
  int orig = blockIdx.x + gridDim.x * blockIdx.y;
  int q = nwg >> 3, r = nwg & 7;
  int xcd = orig & 7, ixc = orig >> 3;
  int logical = (xcd < r ? xcd*(q+1) : r*(q+1) + (xcd-r)*q) + ixc;
  int nn = gridDim.y;
  bmt = logical / nn;
  bnt = logical - bmt*nn;
}

#define ENC_NORM 1.4247939f
#define GC_C     6.3775511f
#define GC_2CD   1.3426423f
#define GC_CD2   0.070665395f
#define GC_S1    0.86820227f

typedef __attribute__((ext_vector_type(4))) float f32x4;
typedef __attribute__((ext_vector_type(8))) short bf16x8;

// Conv feature maps use interleaved channel order: stored channel c' holds
// original channel orig(c') = 16*(c'&1) + (c'>>1).

// ================= unified weight prep =================
__global__ __launch_bounds__(256) void k_prep(
    const float* __restrict__ g_w1, const float* __restrict__ g_w2,
    const float* __restrict__ g_w3, const float* __restrict__ g_w4,
    const float* __restrict__ h_w1, const float* __restrict__ h_w2,
    const float* __restrict__ h_w3, const float* __restrict__ post_w,
    const float* __restrict__ conv_w2, const float* __restrict__ conv_w3,
    const float* __restrict__ conv_w4, const float* __restrict__ conv_w1,
    const float* __restrict__ f_w1, const float* __restrict__ f_w2,
    unsigned short* __restrict__ WT)
{
  int e = blockIdx.x*256 + threadIdx.x;
  float v;
  if (e < 262144) {
    int nn = e >> 8, kk = e & 255;
    v = (nn < 512) ? g_w1[kk*512 + nn] : g_w1[(256+kk)*512 + (nn-512)];
  } else if (e < 524288) {
    int r = e - 262144; int nn = r >> 9, kk = r & 511;
    v = g_w2[kk*512 + nn];
  } else if (e < 786432) {
    int r = e - 524288; int nn = r >> 9, kk = r & 511;
    v = g_w3[kk*512 + nn];
  } else if (e < 917504) {
    int r = e - 786432; int nn = r >> 9, kk = r & 511;
    v = g_w4[kk*256 + nn];
  } else if (e < 1310720) {
    int r = e - 917504; int i = r >> 17; int q = r & 131071;
    int nn = q >> 8, kk = q & 255;
    v = (nn < 256) ? h_w1[i*131072 + kk*256 + nn]
                   : h_w1[i*131072 + (256+kk)*256 + (nn-256)];
  } else if (e < 1507328) {
    int r = e - 1310720; int i = r >> 16; int q = r & 65535;
    int nn = q >> 8, kk = q & 255;
    v = h_w2[i*65536 + kk*256 + nn];
  } else if (e < 1703936) {
    int r = e - 1507328; int i = r >> 16; int q = r & 65535;
    int nn = q >> 8, kk = q & 255;
    v = h_w3[i*65536 + kk*256 + nn];
  } else if (e < 1835008) {
    int r = e - 1703936; int np = r >> 9, kp = r & 511;
    int px = kp >> 5, c = kp & 31;
    int co = ((c & 1) << 4) | (c >> 1);          // undo channel interleave
    v = (np < 247) ? post_w[(co*16+px)*247 + np] : 0.f;
  } else if (e < 1862656) {
    int r = e - 1835008; int which = r / 9216; int q = r % 9216;
    int tap = q >> 10, o = (q >> 5) & 31, c = q & 31;
    int co = ((c & 1) << 4) | (c >> 1);          // input channels interleaved
    const float* w = which==0 ? conv_w2 : (which==1 ? conv_w3 : conv_w4);
    v = w[(o*32+co)*9 + tap];
  } else if (e < 1871872) {
    int r = e - 1862656; int tap = r >> 10, o = (r >> 5) & 31, c = r & 31;
    v = (c < 20) ? conv_w1[(o*20+c)*9 + tap] : 0.f;
  } else if (e < 1937408) {
    int r = e - 1871872; int nn = r >> 8, kk = r & 255;
    v = f_w1[kk*256 + nn];
  } else {
    int r = e - 1937408; int nn = r >> 8, kk = r & 255;
    v = f_w2[kk*256 + nn];
  }
  WT[e] = f2bf(v);
}

// ================= conv1: fused encoding + MFMA implicit GEMM =================
__global__ __launch_bounds__(256, 1) void k_conv1m(
    const float* __restrict__ batch, const unsigned short* __restrict__ wc1,
    const float* __restrict__ bias, unsigned short* __restrict__ y)
{
  __shared__ unsigned short ench[7][41][40];
  int n = blockIdx.x;
  int h = blockIdx.y;
  int c0 = h * 40;
  int OWH = h ? 19 : 20;
  int owbase = h * 20;
  int s0 = blockIdx.z * 7;
  int s1 = blockIdx.z ? 13 : 7;
  int tid = threadIdx.x;
  int lane = tid & 63, wid = tid >> 6;
  int lr = lane & 15, kg = lane >> 4;

  bf16x8 bf0[9], bf1[9];
  #pragma unroll
  for (int tap = 0; tap < 9; ++tap) {
    bf0[tap] = *(const bf16x8*)&wc1[tap*1024 + lr*32 + kg*8];
    bf1[tap] = *(const bf16x8*)&wc1[tap*1024 + (16+lr)*32 + kg*8];
  }
  float b0 = bias[lr], b1 = bias[16 + lr];
  const float S2 = GC_S1 * GC_S1;

  for (int s = s0; s < s1; ++s) {
    int orow0 = s * 3;
    int irow0 = orow0 * 2;
    const float* img = batch + (size_t)n*6400 + irow0*80;
    for (int p = tid; p < 7*41; p += 256) {
      int row = p / 41, hx = p % 41;
      int lc = (hx < 21) ? 2*hx : 2*(hx-21)+1;
      int c = c0 + lc;
      if (c > 78) continue;
      float x = img[row*80 + c];
      float E = __expf(x * (4.0f/255.0f) - 2.0f);
      float t = 1.0f - 2.0f*__builtin_amdgcn_rcpf(E + 1.0f);
      float z = t - 1.0f;
      float e = ENC_NORM * __expf(-GC_C*z*z);
      float rg = __expf(-GC_2CD*z - GC_CD2);
      unsigned int pk[16];
      #pragma unroll
      for (int cp = 0; cp < 10; ++cp) {
        float e1 = e * rg;
        pk[cp] = pack_bf2(e, e1);
        e  = e1 * rg * GC_S1;
        rg = rg * S2;
      }
      #pragma unroll
      for (int cp = 10; cp < 16; ++cp) pk[cp] = 0u;
      unsigned short* dst = &ench[row][hx][0];
      *(uint4*)(dst)      = *(uint4*)&pk[0];
      *(uint4*)(dst + 8)  = *(uint4*)&pk[4];
      *(uint4*)(dst + 16) = *(uint4*)&pk[8];
      *(uint4*)(dst + 24) = *(uint4*)&pk[12];
    }
    __syncthreads();

    int totpx = 3 * OWH;
    {
      int t = wid;
      int pa = t*16 + lr;
      int pc = (pa < totpx) ? pa : (totpx - 1);
      int ohl = pc / OWH, lw = pc % OWH;
      f32x4 acc0 = {0.f,0.f,0.f,0.f}, acc1 = {0.f,0.f,0.f,0.f};
      #pragma unroll
      for (int kh = 0; kh < 3; ++kh) {
        int r = ohl*2 + kh;
        #pragma unroll
        for (int kw = 0; kw < 3; ++kw) {
          int hidx = (kw == 1) ? (21 + lw) : (lw + (kw >> 1));
          bf16x8 a = *(const bf16x8*)&ench[r][hidx][kg*8];
          int tap = kh*3 + kw;
          acc0 = __builtin_amdgcn_mfma_f32_16x16x32_bf16(a, bf0[tap], acc0, 0, 0, 0);
          acc1 = __builtin_amdgcn_mfma_f32_16x16x32_bf16(a, bf1[tap], acc1, 0, 0, 0);
        }
      }
      #pragma unroll
      for (int rr = 0; rr < 4; ++rr) {
        int ps = t*16 + kg*4 + rr;
        if (ps < totpx) {
          int soh = orow0 + ps / OWH, sow = owbase + ps % OWH;
          unsigned short* op = y + (((size_t)n*39 + soh)*39 + sow)*32;
          *(unsigned int*)(op + 2*lr) =
            pack_bf2(lrelu(acc0[rr] + b0), lrelu(acc1[rr] + b1));
        }
      }
    }
    __syncthreads();
  }
}

// ---------------- conv2: bf16 MFMA implicit GEMM, slab loop ----------------
template<int H, int W, int OH, int OW, int ROWS, int SLABS>
__global__ __launch_bounds__(256, 1) void k_cmfma(
    const unsigned short* __restrict__ in, const unsigned short* __restrict__ wc,
    const float* __restrict__ bias, unsigned short* __restrict__ out)
{
  constexpr int IR = 2*ROWS + 1;
  constexpr int EV = (W + 1) / 2;
  __shared__ unsigned short xs[IR][W][40];
  int n = blockIdx.x;
  int tid = threadIdx.x;
  int lane = tid & 63, wid = tid >> 6;
  int lr = lane & 15, kg = lane >> 4;

  bf16x8 bf0[9], bf1[9];
  #pragma unroll
  for (int tap = 0; tap < 9; ++tap) {
    bf0[tap] = *(const bf16x8*)&wc[(tap*32 + lr)*32      + kg*8];
    bf1[tap] = *(const bf16x8*)&wc[(tap*32 + 16 + lr)*32 + kg*8];
  }
  float b0 = bias[lr], b1 = bias[16 + lr];

  for (int s = 0; s < SLABS; ++s) {
    int orow0 = (blockIdx.y * SLABS + s) * ROWS;
    if (orow0 >= OH) break;
    int nrows = min(ROWS, OH - orow0);
    int irow0 = orow0 * 2;
    int ir = min(2*nrows + 1, H - irow0);

    const unsigned short* ip = in + ((size_t)n*H + irow0)*W*32;
    int npx = ir * W;
    for (int p = tid; p < npx; p += 256) {
      const uint4* src = (const uint4*)(ip + (size_t)p*32);
      uint4 v0 = src[0], v1 = src[1], v2 = src[2], v3 = src[3];
      int r = p / W, col = p % W;
      int hx = (col & 1) ? EV + (col >> 1) : (col >> 1);
      unsigned short* dst = &xs[r][hx][0];
      *(uint4*)(dst)      = v0;
      *(uint4*)(dst + 8)  = v1;
      *(uint4*)(dst + 16) = v2;
      *(uint4*)(dst + 24) = v3;
    }
    __syncthreads();

    int totpx = nrows * OW;
    int ntiles = (totpx + 15) >> 4;
    for (int t = wid; t < ntiles; t += 4) {
      int pa = t*16 + lr;
      int pc = (pa < totpx) ? pa : 0;
      int oh = pc / OW, ow = pc % OW;
      f32x4 acc0 = {0.f,0.f,0.f,0.f}, acc1 = {0.f,0.f,0.f,0.f};
      #pragma unroll
      for (int kh = 0; kh < 3; ++kh)
        #pragma unroll
        for (int kw = 0; kw < 3; ++kw) {
          int hidx = (kw == 1) ? (EV + ow) : (ow + (kw >> 1));
          bf16x8 a = *(const bf16x8*)&xs[oh*2 + kh][hidx][kg*8];
          acc0 = __builtin_amdgcn_mfma_f32_16x16x32_bf16(a, bf0[kh*3+kw], acc0, 0, 0, 0);
          acc1 = __builtin_amdgcn_mfma_f32_16x16x32_bf16(a, bf1[kh*3+kw], acc1, 0, 0, 0);
        }
      #pragma unroll
      for (int rr = 0; rr < 4; ++rr) {
        int ps = t*16 + kg*4 + rr;
        if (ps < totpx) {
          int soh = orow0 + ps / OW, sow = ps % OW;
          unsigned short* op = out + (((size_t)n*OH + soh)*OW + sow)*32;
          *(unsigned int*)(op + 2*lr) =
            pack_bf2(lrelu(acc0[rr] + b0), lrelu(acc1[rr] + b1));
        }
      }
    }
    __syncthreads();
  }
}

// ---------------- fused conv3+conv4 (per image) ----------------
__global__ __launch_bounds__(256, 1) void k_conv34(
    const unsigned short* __restrict__ in,
    const unsigned short* __restrict__ wc3, const float* __restrict__ b3,
    const unsigned short* __restrict__ wc4, const float* __restrict__ b4,
    unsigned short* __restrict__ out)
{
  __shared__ unsigned short xs[19][19][40];
  __shared__ unsigned short ys[9][9][40];
  int n = blockIdx.x;
  int tid = threadIdx.x;
  int lane = tid & 63, wid = tid >> 6;
  int lr = lane & 15, kg = lane >> 4;

  bf16x8 c3a[9], c3b[9], c4a[9], c4b[9];
  #pragma unroll
  for (int tap = 0; tap < 9; ++tap) {
    c3a[tap] = *(const bf16x8*)&wc3[(tap*32 + lr)*32      + kg*8];
    c3b[tap] = *(const bf16x8*)&wc3[(tap*32 + 16 + lr)*32 + kg*8];
    c4a[tap] = *(const bf16x8*)&wc4[(tap*32 + lr)*32      + kg*8];
    c4b[tap] = *(const bf16x8*)&wc4[(tap*32 + 16 + lr)*32 + kg*8];
  }
  float b30 = b3[lr], b31 = b3[16+lr];
  float b40 = b4[lr], b41 = b4[16+lr];

  const unsigned short* ip = in + (size_t)n*19*19*32;
  for (int p = tid; p < 361; p += 256) {
    const uint4* src = (const uint4*)(ip + (size_t)p*32);
    uint4 v0 = src[0], v1 = src[1], v2 = src[2], v3 = src[3];
    int r = p / 19, col = p % 19;
    int hx = (col & 1) ? 10 + (col >> 1) : (col >> 1);
    unsigned short* dst = &xs[r][hx][0];
    *(uint4*)(dst)      = v0;
    *(uint4*)(dst + 8)  = v1;
    *(uint4*)(dst + 16) = v2;
    *(uint4*)(dst + 24) = v3;
  }
  __syncthreads();

  for (int t = wid; t < 6; t += 4) {
    int pa = t*16 + lr;
    int pc = (pa < 81) ? pa : 0;
    int oh = pc / 9, ow = pc % 9;
    f32x4 acc0 = {0.f,0.f,0.f,0.f}, acc1 = {0.f,0.f,0.f,0.f};
    #pragma unroll
    for (int kh = 0; kh < 3; ++kh)
      #pragma unroll
      for (int kw = 0; kw < 3; ++kw) {
        int hidx = (kw == 1) ? (10 + ow) : (ow + (kw >> 1));
        bf16x8 a = *(const bf16x8*)&xs[oh*2 + kh][hidx][kg*8];
        acc0 = __builtin_amdgcn_mfma_f32_16x16x32_bf16(a, c3a[kh*3+kw], acc0, 0, 0, 0);
        acc1 = __builtin_amdgcn_mfma_f32_16x16x32_bf16(a, c3b[kh*3+kw], acc1, 0, 0, 0);
      }
    #pragma unroll
    for (int rr = 0; rr < 4; ++rr) {
      int ps = t*16 + kg*4 + rr;
      if (ps < 81) {
        int soh = ps / 9, sow = ps % 9;
        int hx2 = (sow & 1) ? 5 + (sow >> 1) : (sow >> 1);
        *(unsigned int*)&ys[soh][hx2][2*lr] =
          pack_bf2(lrelu(acc0[rr] + b30), lrelu(acc1[rr] + b31));
      }
    }
  }
  __syncthreads();

  if (wid == 0) {
    int pc = lr;
    int oh = pc >> 2, ow = pc & 3;
    f32x4 acc0 = {0.f,0.f,0.f,0.f}, acc1 = {0.f,0.f,0.f,0.f};
    #pragma unroll
    for (int kh = 0; kh < 3; ++kh)
      #pragma unroll
      for (int kw = 0; kw < 3; ++kw) {
        int hidx = (kw == 1) ? (5 + ow) : (ow + (kw >> 1));
        bf16x8 a = *(const bf16x8*)&ys[oh*2 + kh][hidx][kg*8];
        acc0 = __builtin_amdgcn_mfma_f32_16x16x32_bf16(a, c4a[kh*3+kw], acc0, 0, 0, 0);
        acc1 = __builtin_amdgcn_mfma_f32_16x16x32_bf16(a, c4b[kh*3+kw], acc1, 0, 0, 0);
      }
    #pragma unroll
    for (int rr = 0; rr < 4; ++rr) {
      int ps = kg*4 + rr;
      int soh = ps >> 2, sow = ps & 3;
      unsigned short* op = out + (((size_t)n*4 + soh)*4 + sow)*32;
      *(unsigned int*)(op + 2*lr) =
        pack_bf2(lrelu(acc0[rr] + b40), lrelu(acc1[rr] + b41));
    }
  }
}

// ---------------- bf16 MFMA GEMM via global_load_lds + XOR-swizzled LDS ----------------
template<int OUT_BF16, int ACT>
__global__ __launch_bounds__(256) void k_mgemm(
    const unsigned short* __restrict__ A, const unsigned short* __restrict__ Wt,
    const float* __restrict__ bias, void* __restrict__ Cv,
    int M, int N, int K)
{
  __shared__ unsigned short As[128*64];
  __shared__ unsigned short Bs[128*64];
  int bmt, bnt; xcd_tiles(bmt, bnt);
  int bm = bmt * 128;
  int bn = bnt * 128;
  int tid = threadIdx.x;
  int wid = tid >> 6, lane = tid & 63;
  int wr = (wid >> 1) * 64, wc = (wid & 1) * 64;
  int lr = lane & 15, kg = lane >> 4;

  int srow = lane >> 3;
  int ssw  = ((lane & 7) * 16) ^ (srow << 4);
  int rsw  = (lr & 7) << 4;

  f32x4 acc[4][4];
  #pragma unroll
  for (int i = 0; i < 4; ++i)
    #pragma unroll
    for (int j = 0; j < 4; ++j)
      acc[i][j] = (f32x4){0.f,0.f,0.f,0.f};

  for (int k0 = 0; k0 < K; k0 += 64) {
    #pragma unroll
    for (int i = 0; i < 4; ++i) {
      int rowc = wid*32 + i*8;
      int row  = rowc + srow;
      gload16((const char*)&A[(size_t)(bm + row)*K + k0] + ssw, &As[rowc*64]);
      gload16((const char*)&Wt[(size_t)(bn + row)*K + k0] + ssw, &Bs[rowc*64]);
    }
    __syncthreads();
    #pragma unroll
    for (int ks = 0; ks < 2; ++ks) {
      int roff = ((ks*64 + kg*16) ^ rsw) >> 1;
      bf16x8 a[4], b[4];
      #pragma unroll
      for (int i = 0; i < 4; ++i) {
        a[i] = *(const bf16x8*)&As[(wr + i*16 + lr)*64 + roff];
        b[i] = *(const bf16x8*)&Bs[(wc + i*16 + lr)*64 + roff];
      }
      #pragma unroll
      for (int i = 0; i < 4; ++i)
        #pragma unroll
        for (int j = 0; j < 4; ++j)
          acc[i][j] = __builtin_amdgcn_mfma_f32_16x16x32_bf16(a[i], b[j], acc[i][j], 0, 0, 0);
    }
    __syncthreads();
  }
  int r0 = (lane >> 4) * 4;
  #pragma unroll
  for (int i = 0; i < 4; ++i) {
    #pragma unroll
    for (int j = 0; j < 4; ++j) {
      int col = bn + wc + j*16 + lr;
      float bv = bias ? bias[col] : 0.f;
      #pragma unroll
      for (int rr = 0; rr < 4; ++rr) {
        int row = bm + wr + i*16 + r0 + rr;
        float v = acc[i][j][rr] + bv;
        if (ACT) v = lrelu(v);
        if (OUT_BF16) ((unsigned short*)Cv)[(size_t)row*N + col] = f2bf(v);
        else          ((float*)Cv)[(size_t)row*N + col] = v;
      }
    }
  }
}

// ---------------- pair GEMM: fused expand + GEMM ----------------
__global__ __launch_bounds__(256) void k_pgemm(
    const unsigned short* __restrict__ UV, const unsigned short* __restrict__ Wt,
    const float* __restrict__ abias, const float* __restrict__ obias,
    unsigned short* __restrict__ C, int M, int N, int K)
{
  __shared__ unsigned short As[128*64];
  __shared__ unsigned short Bs[128*64];
  __shared__ float absm[512];
  int bmt, bnt; xcd_tiles(bmt, bnt);
  int bm = bmt * 128;
  int bn = bnt * 128;
  int tid = threadIdx.x;
  int wid = tid >> 6, lane = tid & 63;
  int wr = (wid >> 1) * 64, wc = (wid & 1) * 64;
  int lr = lane & 15, kg = lane >> 4;
  int ld = 2*K;

  int srow = lane >> 3;
  int ssw  = ((lane & 7) * 16) ^ (srow << 4);
  int rsw  = (lr & 7) << 4;

  for (int idx = tid; idx < K; idx += 256) absm[idx] = abias[idx];

  int urow[4], vrow[4], arow[4], asw[4];
  #pragma unroll
  for (int i = 0; i < 4; ++i) {
    int ch = tid + (i << 8);
    int r = ch >> 3;
    int m = bm + r;
    int n = m / 81; int rem = m - n*81;
    int ii = rem / 9; int jj = rem - ii*9;
    urow[i] = n*9 + ii; vrow[i] = n*9 + jj;
    arow[i] = r;
    asw[i] = (((ch & 7) * 16) ^ ((r & 7) << 4)) >> 1;
  }
  __syncthreads();

  f32x4 acc[4][4];
  #pragma unroll
  for (int i = 0; i < 4; ++i)
    #pragma unroll
    for (int j = 0; j < 4; ++j)
      acc[i][j] = (f32x4){0.f,0.f,0.f,0.f};

  for (int k0 = 0; k0 < K; k0 += 64) {
    #pragma unroll
    for (int i = 0; i < 4; ++i) {
      int rowc = wid*32 + i*8;
      int row  = rowc + srow;
      gload16((const char*)&Wt[(size_t)(bn + row)*K + k0] + ssw, &Bs[rowc*64]);
    }
    #pragma unroll
    for (int i = 0; i < 4; ++i) {
      int ch = tid + (i << 8);
      int kc = (ch & 7) * 8;
      uint4 u4 = *(const uint4*)&UV[(size_t)urow[i]*ld + k0 + kc];
      uint4 v4 = *(const uint4*)&UV[(size_t)vrow[i]*ld + K + k0 + kc];
      const unsigned short* us = (const unsigned short*)&u4;
      const unsigned short* vs = (const unsigned short*)&v4;
      unsigned int pk[4];
      #pragma unroll
      for (int e2 = 0; e2 < 4; ++e2) {
        float a0 = bf2f(us[2*e2])   + bf2f(vs[2*e2])   + absm[k0 + kc + 2*e2];
        float a1 = bf2f(us[2*e2+1]) + bf2f(vs[2*e2+1]) + absm[k0 + kc + 2*e2+1];
        pk[e2] = pack_bf2(lrelu(a0), lrelu(a1));
      }
      *(uint4*)&As[arow[i]*64 + asw[i]] = *(uint4*)pk;
    }
    __syncthreads();
    #pragma unroll
    for (int ks = 0; ks < 2; ++ks) {
      int roff = ((ks*64 + kg*16) ^ rsw) >> 1;
      bf16x8 a[4], b[4];
      #pragma unroll
      for (int i = 0; i < 4; ++i) {
        a[i] = *(const bf16x8*)&As[(wr + i*16 + lr)*64 + roff];
        b[i] = *(const bf16x8*)&Bs[(wc + i*16 + lr)*64 + roff];
      }
      #pragma unroll
      for (int i = 0; i < 4; ++i)
        #pragma unroll
        for (int j = 0; j < 4; ++j)
          acc[i][j] = __builtin_amdgcn_mfma_f32_16x16x32_bf16(a[i], b[j], acc[i][j], 0, 0, 0);
    }
    __syncthreads();
  }
  int r0 = (lane >> 4) * 4;
  #pragma unroll
  for (int i = 0; i < 4; ++i) {
    #pragma unroll
    for (int j = 0; j < 4; ++j) {
      int col = bn + wc + j*16 + lr;
      float bv = obias[col];
      #pragma unroll
      for (int rr = 0; rr < 4; ++rr) {
        int row = bm + wr + i*16 + r0 + rr;
        C[(size_t)row*N + col] = f2bf(lrelu(acc[i][j][rr] + bv));
      }
    }
  }
}

// ---------------- g1 GEMM with objects built on the fly ----------------
__global__ __launch_bounds__(256) void k_g1o(
    const float* __restrict__ panel, const float* __restrict__ post_b,
    const unsigned short* __restrict__ Wt, unsigned short* __restrict__ C,
    int M, int N, int K)
{
  __shared__ unsigned short As[128*64];
  __shared__ unsigned short Bs[128*64];
  __shared__ float pbs[256];
  int bmt, bnt; xcd_tiles(bmt, bnt);
  int bm = bmt * 128;
  int bn = bnt * 128;
  int tid = threadIdx.x;
  int wid = tid >> 6, lane = tid & 63;
  int wr = (wid >> 1) * 64, wc = (wid & 1) * 64;
  int lr = lane & 15, kg = lane >> 4;

  int srow = lane >> 3;
  int ssw  = ((lane & 7) * 16) ^ (srow << 4);
  int rsw  = (lr & 7) << 4;

  if (tid < 256) pbs[tid] = (tid < 247) ? post_b[tid] : 0.f;

  int srcr[4], slotr[4], arow[4], asw[4];
  #pragma unroll
  for (int i = 0; i < 4; ++i) {
    int ch = tid + (i << 8);
    int r = ch >> 3;
    int m = bm + r;
    int nn = m / 9; int sl = m - nn*9;
    int b = nn >> 3, opt = nn & 7;
    srcr[i] = (sl < 8) ? (b*16 + sl) : (b*16 + 8 + opt);
    slotr[i] = sl;
    arow[i] = r;
    asw[i] = (((ch & 7) * 16) ^ ((r & 7) << 4)) >> 1;
  }
  __syncthreads();

  f32x4 acc[4][4];
  #pragma unroll
  for (int i = 0; i < 4; ++i)
    #pragma unroll
    for (int j = 0; j < 4; ++j)
      acc[i][j] = (f32x4){0.f,0.f,0.f,0.f};

  for (int k0 = 0; k0 < K; k0 += 64) {
    #pragma unroll
    for (int i = 0; i < 4; ++i) {
      int rowc = wid*32 + i*8;
      int row  = rowc + srow;
      gload16((const char*)&Wt[(size_t)(bn + row)*K + k0] + ssw, &Bs[rowc*64]);
    }
    #pragma unroll
    for (int i = 0; i < 4; ++i) {
      int ch = tid + (i << 8);
      int kc = (ch & 7) * 8;
      int kb = k0 + kc;
      const float* pp = &panel[(size_t)srcr[i]*256 + kb];
      unsigned int pk[4];
      #pragma unroll
      for (int e2 = 0; e2 < 4; ++e2) {
        float v0 = pp[2*e2]   + pbs[kb + 2*e2];
        float v1 = pp[2*e2+1] + pbs[kb + 2*e2+1];
        int kk0 = kb + 2*e2, kk1 = kb + 2*e2 + 1;
        if (kk0 >= 247) v0 = (kk0 - 247 == slotr[i]) ? 1.f : 0.f;
        if (kk1 >= 247) v1 = (kk1 - 247 == slotr[i]) ? 1.f : 0.f;
        pk[e2] = pack_bf2(v0, v1);
      }
      *(uint4*)&As[arow[i]*64 + asw[i]] = *(uint4*)pk;
    }
    __syncthreads();
    #pragma unroll
    for (int ks = 0; ks < 2; ++ks) {
      int roff = ((ks*64 + kg*16) ^ rsw) >> 1;
      bf16x8 a[4], b[4];
      #pragma unroll
      for (int i = 0; i < 4; ++i) {
        a[i] = *(const bf16x8*)&As[(wr + i*16 + lr)*64 + roff];
        b[i] = *(const bf16x8*)&Bs[(wc + i*16 + lr)*64 + roff];
      }
      #pragma unroll
      for (int i = 0; i < 4; ++i)
        #pragma unroll
        for (int j = 0; j < 4; ++j)
          acc[i][j] = __builtin_amdgcn_mfma_f32_16x16x32_bf16(a[i], b[j], acc[i][j], 0, 0, 0);
    }
    __syncthreads();
  }
  int r0 = (lane >> 4) * 4;
  #pragma unroll
  for (int i = 0; i < 4; ++i) {
    #pragma unroll
    for (int j = 0; j < 4; ++j) {
      int col = bn + wc + j*16 + lr;
      #pragma unroll
      for (int rr = 0; rr < 4; ++rr) {
        int row = bm + wr + i*16 + r0 + rr;
        C[(size_t)row*N + col] = f2bf(acc[i][j][rr]);
      }
    }
  }
}

// ---------------- sum over j (vectorized x8); WSJ: write fp32, WSJB: write bf16 ----------------
template<int WSJ, int WSJB>
__global__ void k_sumj(const unsigned short* __restrict__ Z, float* __restrict__ SJ,
                       unsigned short* __restrict__ SJb, int C)
{
  int idx = blockIdx.x*256 + threadIdx.x;
  int vpr = C >> 3;
  int orow = idx / vpr, kv = (idx - orow*vpr) << 3;
  int n = orow / 9, i = orow % 9;
  const unsigned short* base = Z + (size_t)(n*81 + i*9)*C + kv;
  float s[8];
  #pragma unroll
  for (int e = 0; e < 8; ++e) s[e] = 0.f;
  #pragma unroll
  for (int j = 0; j < 9; ++j) {
    bf16x8 v = *(const bf16x8*)(base + (size_t)j*C);
    #pragma unroll
    for (int e = 0; e < 8; ++e) s[e] += bf2f(((const unsigned short*)&v)[e]);
  }
  if (WSJ) {
    float* so = SJ + (size_t)orow*C + kv;
    #pragma unroll
    for (int e = 0; e < 8; ++e) so[e] = s[e];
  }
  if (WSJB) {
    unsigned int pk[4];
    #pragma unroll
    for (int e2 = 0; e2 < 4; ++e2) pk[e2] = pack_bf2(s[2*e2], s[2*e2+1]);
    *(uint4*)(SJb + (size_t)orow*C + kv) = *(uint4*)pk;
  }
}

// ---------------- sum over i (vectorized x4) ----------------
__global__ void k_hsum(const float* __restrict__ SJ, float* __restrict__ HS,
                       unsigned short* __restrict__ HSb)
{
  int idx = blockIdx.x*256 + threadIdx.x;
  int n = idx >> 6, kc = (idx & 63) << 2;
  const float* base = SJ + (size_t)n*9*256 + kc;
  float4 s = {0.f,0.f,0.f,0.f};
  #pragma unroll
  for (int i = 0; i < 9; ++i) {
    float4 v = *(const float4*)(base + (size_t)i*256);
    s.x += v.x; s.y += v.y; s.z += v.z; s.w += v.w;
  }
  *(float4*)(HS + (size_t)n*256 + kc) = s;
  unsigned int pk[2];
  pk[0] = pack_bf2(s.x, s.y);
  pk[1] = pack_bf2(s.z, s.w);
  *(uint2*)(HSb + (size_t)n*256 + kc) = *(uint2*)pk;
}

// ---------------- fused tail ----------------
__global__ __launch_bounds__(256) void k_tailfin(
    const float* __restrict__ HS, const unsigned short* __restrict__ F2,
    const float* __restrict__ ffw, const float* __restrict__ ffb,
    float* __restrict__ out)
{
  __shared__ float red[256];
  __shared__ float wsm[256];
  int tid = threadIdx.x;
  wsm[tid] = ffw[tid];
  float s = 0.f;
  for (int j = 0; j < 256; ++j) { float v = HS[j*256 + tid]; s += v*v; }
  red[tid] = s; __syncthreads();
  for (int off = 128; off > 0; off >>= 1) { if (tid < off) red[tid] += red[tid + off]; __syncthreads(); }
  float hsq = red[0];
  __syncthreads();
  float r = ffb[0];
  for (int k = 0; k < 256; ++k) r += bf2f(F2[(size_t)tid*256 + k])*wsm[k];
  red[tid] = r*r; __syncthreads();
  for (int off = 128; off > 0; off >>= 1) { if (tid < off) red[tid] += red[tid + off]; __syncthreads(); }
  out[tid] = r;
  if (tid == 0) out[256] = hsq/65536.0f + red[0]/256.0f;
}

extern "C" void kernel_launch(void* const* d_in, const int* in_sizes, int n_in,
                              void* d_out, int out_size, void* d_ws, size_t ws_size,
                              hipStream_t stream)
{
  const float* batch   = (const float*)d_in[0];
  const float* conv_w1 = (const float*)d_in[1];
  const float* conv_b1 = (const float*)d_in[2];
  const float* conv_w2 = (const float*)d_in[3];
  const float* conv_b2 = (const float*)d_in[4];
  const float* conv_w3 = (const float*)d_in[5];
  const float* conv_b3 = (const float*)d_in[6];
  const float* conv_w4 = (const float*)d_in[7];
  const float* conv_b4 = (const float*)d_in[8];
  const float* post_w  = (const float*)d_in[9];
  const float* post_b  = (const float*)d_in[10];
  const float* g_w1    = (const float*)d_in[11];
  const float* g_b1    = (const float*)d_in[12];
  const float* g_w2    = (const float*)d_in[13];
  const float* g_b2    = (const float*)d_in[14];
  const float* g_w3    = (const float*)d_in[15];
  const float* g_b3    = (const float*)d_in[16];
  const float* g_w4    = (const float*)d_in[17];
  const float* g_b4    = (const float*)d_in[18];
  const float* h_w1    = (const float*)d_in[19];
  const float* h_b1    = (const float*)d_in[20];
  const float* h_w2    = (const float*)d_in[21];
  const float* h_b2    = (const float*)d_in[22];
  const float* h_w3    = (const float*)d_in[23];
  const float* h_b3    = (const float*)d_in[24];
  const float* f_w1    = (const float*)d_in[25];
  const float* f_b1    = (const float*)d_in[26];
  const float* f_w2    = (const float*)d_in[27];
  const float* f_b2    = (const float*)d_in[28];
  const float* ff_w    = (const float*)d_in[29];
  const float* ff_b    = (const float*)d_in[30];

  char* wsb = (char*)d_ws;
  const size_t off_Y1    = 0;
  const size_t off_Y2    = 52000000;
  const size_t off_Y4    = 67000000;
  const size_t off_PANEL = 68000000;
  const size_t off_WT    = 132000000;
  const size_t off_Pb    = 0;
  const size_t off_Qb    = 22000000;
  const size_t off_UV    = 44000000;
  const size_t off_SJ    = 56000000;
  const size_t off_SJb   = 59000000;
  const size_t off_HS    = 61000000;
  const size_t off_HSb   = 61500000;
  const size_t off_F1    = 62000000;
  const size_t off_F2    = 63000000;

  unsigned short* WT = (unsigned short*)(wsb + off_WT);
  const size_t wt_g1   = 0;
  const size_t wt_g2   = 262144;
  const size_t wt_g3   = 524288;
  const size_t wt_g4   = 786432;
  const size_t wt_h1   = 917504;
  const size_t wt_h2   = 1310720;
  const size_t wt_h3   = 1507328;
  const size_t wt_post = 1703936;
  const size_t wt_cw2  = 1835008;
  const size_t wt_cw3  = 1844224;
  const size_t wt_cw4  = 1853440;
  const size_t wt_cw1  = 1862656;
  const size_t wt_f1   = 1871872;
  const size_t wt_f2   = 1937408;

  dim3 b256(256);

  k_prep<<<dim3(7824), b256, 0, stream>>>(g_w1, g_w2, g_w3, g_w4, h_w1, h_w2, h_w3,
                                          post_w, conv_w2, conv_w3, conv_w4, conv_w1,
                                          f_w1, f_w2, WT);

  unsigned short* Y1 = (unsigned short*)(wsb + off_Y1);
  unsigned short* Y2 = (unsigned short*)(wsb + off_Y2);
  unsigned short* Y4 = (unsigned short*)(wsb + off_Y4);
  float* PANEL = (float*)(wsb + off_PANEL);

  k_conv1m<<<dim3(512,2,2), b256, 0, stream>>>(batch, WT + wt_cw1, conv_b1, Y1);
  k_cmfma<39,39,19,19,5,2><<<dim3(512,2), b256, 0, stream>>>(Y1, WT + wt_cw2, conv_b2, Y2);
  k_conv34<<<dim3(512), b256, 0, stream>>>(Y2, WT + wt_cw3, conv_b3, WT + wt_cw4, conv_b4, Y4);

  k_mgemm<0,0><<<dim3(4,2), b256, 0, stream>>>(Y4, WT + wt_post, nullptr, PANEL, 512,256,512);

  unsigned short* Pb  = (unsigned short*)(wsb + off_Pb);
  unsigned short* Qb  = (unsigned short*)(wsb + off_Qb);
  unsigned short* UVb = (unsigned short*)(wsb + off_UV);
  unsigned short* SJb = (unsigned short*)(wsb + off_SJb);
  float* SJ = (float*)(wsb + off_SJ);
  float* HS = (float*)(wsb + off_HS);
  unsigned short* HSb = (unsigned short*)(wsb + off_HSb);
  unsigned short* F1 = (unsigned short*)(wsb + off_F1);
  unsigned short* F2 = (unsigned short*)(wsb + off_F2);

  // g-MLP (objects folded into g1 staging)
  k_g1o<<<dim3(18,8), b256, 0, stream>>>(PANEL, post_b, WT + wt_g1, UVb, 2304,1024,256);
  k_pgemm<<<dim3(162,4), b256, 0, stream>>>(UVb, WT + wt_g2, g_b1, g_b2, Qb, 20736,512,512);
  k_mgemm<1,1><<<dim3(162,4), b256, 0, stream>>>(Qb, WT + wt_g3, g_b3, Pb, 20736,512,512);
  k_mgemm<1,1><<<dim3(162,2), b256, 0, stream>>>(Pb, WT + wt_g4, g_b4, Qb, 20736,256,512);
  k_sumj<0,1><<<dim3(288), b256, 0, stream>>>(Qb, SJ, SJb, 256);

  // h loop
  for (int i = 0; i < 3; ++i) {
    k_mgemm<1,0><<<dim3(18,4), b256, 0, stream>>>(SJb, WT + wt_h1 + (size_t)i*131072, nullptr, UVb, 2304,512,256);
    k_pgemm<<<dim3(162,2), b256, 0, stream>>>(UVb, WT + wt_h2 + (size_t)i*65536, h_b1 + i*256, h_b2 + i*256, Qb, 20736,256,256);
    k_mgemm<1,1><<<dim3(162,2), b256, 0, stream>>>(Qb, WT + wt_h3 + (size_t)i*65536, h_b3 + i*256, Pb, 20736,256,256);
    if (i < 2) k_sumj<0,1><<<dim3(288), b256, 0, stream>>>(Pb, SJ, SJb, 256);
    else       k_sumj<1,0><<<dim3(288), b256, 0, stream>>>(Pb, SJ, SJb, 256);
  }

  // head
  k_hsum<<<dim3(64), b256, 0, stream>>>(SJ, HS, HSb);
  k_mgemm<1,1><<<dim3(2,2), b256, 0, stream>>>(HSb, WT + wt_f1, f_b1, F1, 256,256,256);
  k_mgemm<1,1><<<dim3(2,2), b256, 0, stream>>>(F1,  WT + wt_f2, f_b2, F2, 256,256,256);
  k_tailfin<<<dim3(1), b256, 0, stream>>>(HS, F2, ff_w, ff_b, (float*)d_out);
}

// Round 19
// 333.478 us; speedup vs baseline: 1.0133x; 1.0133x over previous
//
#include <hip/hip_runtime.h>
#include <hip/hip_bf16.h>
#include <math.h>

static __device__ __forceinline__ float lrelu(float v){ return v > 0.0f ? v : 0.01f*v; }

static __device__ __forceinline__ unsigned short f2bf(float f){
  unsigned int u = __float_as_uint(f);
  unsigned int r = (u + 0x7fffu + ((u >> 16) & 1u)) >> 16;
  return (unsigned short)r;
}
static __device__ __forceinline__ float bf2f(unsigned short u){
  return __uint_as_float(((unsigned int)u) << 16);
}
static __device__ __forceinline__ unsigned int pack_bf2(float lo, float hi){
  __hip_bfloat162 bb = __float22bfloat162_rn(make_float2(lo, hi));
  return *reinterpret_cast<unsigned int*>(&bb);
}
static __device__ __forceinline__ void gload16(const void* g, void* l){
  __builtin_amdgcn_global_load_lds(
    (const __attribute__((address_space(1))) void*)(const void*)g,
    (__attribute__((address_space(3))) void*)l, 16, 0, 0);
}
// LDS-only barrier: drain LDS ops, leave global stores in flight (avoids the
// vmcnt(0) store-drain that __syncthreads() forces before s_barrier).
static __device__ __forceinline__ void barrier_lgkm(){
  asm volatile("s_waitcnt lgkmcnt(0)" ::: "memory");
  __builtin_amdgcn_s_barrier();
}

#define ENC_NORM 1.4247939f
#define GC_C     6.3775511f
#define GC_2CD   1.3426423f
#define GC_CD2   0.070665395f
#define GC_S1    0.86820227f

typedef __attribute__((ext_vector_type(4))) float f32x4;
typedef __attribute__((ext_vector_type(8))) short bf16x8;

// Conv feature maps use interleaved channel order: stored channel c' holds
// original channel orig(c') = 16*(c'&1) + (c'>>1).

// ================= unified weight prep =================
__global__ __launch_bounds__(256) void k_prep(
    const float* __restrict__ g_w1, const float* __restrict__ g_w2,
    const float* __restrict__ g_w3, const float* __restrict__ g_w4,
    const float* __restrict__ h_w1, const float* __restrict__ h_w2,
    const float* __restrict__ h_w3, const float* __restrict__ post_w,
    const float* __restrict__ conv_w2, const float* __restrict__ conv_w3,
    const float* __restrict__ conv_w4, const float* __restrict__ conv_w1,
    const float* __restrict__ f_w1, const float* __restrict__ f_w2,
    unsigned short* __restrict__ WT)
{
  int e = blockIdx.x*256 + threadIdx.x;
  float v;
  if (e < 262144) {
    int nn = e >> 8, kk = e & 255;
    v = (nn < 512) ? g_w1[kk*512 + nn] : g_w1[(256+kk)*512 + (nn-512)];
  } else if (e < 524288) {
    int r = e - 262144; int nn = r >> 9, kk = r & 511;
    v = g_w2[kk*512 + nn];
  } else if (e < 786432) {
    int r = e - 524288; int nn = r >> 9, kk = r & 511;
    v = g_w3[kk*512 + nn];
  } else if (e < 917504) {
    int r = e - 786432; int nn = r >> 9, kk = r & 511;
    v = g_w4[kk*256 + nn];
  } else if (e < 1310720) {
    int r = e - 917504; int i = r >> 17; int q = r & 131071;
    int nn = q >> 8, kk = q & 255;
    v = (nn < 256) ? h_w1[i*131072 + kk*256 + nn]
                   : h_w1[i*131072 + (256+kk)*256 + (nn-256)];
  } else if (e < 1507328) {
    int r = e - 1310720; int i = r >> 16; int q = r & 65535;
    int nn = q >> 8, kk = q & 255;
    v = h_w2[i*65536 + kk*256 + nn];
  } else if (e < 1703936) {
    int r = e - 1507328; int i = r >> 16; int q = r & 65535;
    int nn = q >> 8, kk = q & 255;
    v = h_w3[i*65536 + kk*256 + nn];
  } else if (e < 1835008) {
    int r = e - 1703936; int np = r >> 9, kp = r & 511;
    int px = kp >> 5, c = kp & 31;
    int co = ((c & 1) << 4) | (c >> 1);          // undo channel interleave
    v = (np < 247) ? post_w[(co*16+px)*247 + np] : 0.f;
  } else if (e < 1862656) {
    int r = e - 1835008; int which = r / 9216; int q = r % 9216;
    int tap = q >> 10, o = (q >> 5) & 31, c = q & 31;
    int co = ((c & 1) << 4) | (c >> 1);          // input channels interleaved
    const float* w = which==0 ? conv_w2 : (which==1 ? conv_w3 : conv_w4);
    v = w[(o*32+co)*9 + tap];
  } else if (e < 1871872) {
    int r = e - 1862656; int tap = r >> 10, o = (r >> 5) & 31, c = r & 31;
    v = (c < 20) ? conv_w1[(o*20+c)*9 + tap] : 0.f;
  } else if (e < 1937408) {
    int r = e - 1871872; int nn = r >> 8, kk = r & 255;
    v = f_w1[kk*256 + nn];
  } else {
    int r = e - 1937408; int nn = r >> 8, kk = r & 255;
    v = f_w2[kk*256 + nn];
  }
  WT[e] = f2bf(v);
}

// ================= conv1: fused encoding + MFMA implicit GEMM =================
__global__ __launch_bounds__(256, 1) void k_conv1m(
    const float* __restrict__ batch, const unsigned short* __restrict__ wc1,
    const float* __restrict__ bias, unsigned short* __restrict__ y)
{
  __shared__ unsigned short ench[7][41][40];
  int n = blockIdx.x;
  int h = blockIdx.y;
  int c0 = h * 40;
  int OWH = h ? 19 : 20;
  int owbase = h * 20;
  int s0 = blockIdx.z * 7;
  int s1 = blockIdx.z ? 13 : 7;
  int tid = threadIdx.x;
  int lane = tid & 63, wid = tid >> 6;
  int lr = lane & 15, kg = lane >> 4;

  bf16x8 bf0[9], bf1[9];
  #pragma unroll
  for (int tap = 0; tap < 9; ++tap) {
    bf0[tap] = *(const bf16x8*)&wc1[tap*1024 + lr*32 + kg*8];
    bf1[tap] = *(const bf16x8*)&wc1[tap*1024 + (16+lr)*32 + kg*8];
  }
  float b0 = bias[lr], b1 = bias[16 + lr];
  const float S2 = GC_S1 * GC_S1;

  for (int s = s0; s < s1; ++s) {
    int orow0 = s * 3;
    int irow0 = orow0 * 2;
    const float* img = batch + (size_t)n*6400 + irow0*80;
    for (int p = tid; p < 7*41; p += 256) {
      int row = p / 41, hx = p % 41;
      int lc = (hx < 21) ? 2*hx : 2*(hx-21)+1;
      int c = c0 + lc;
      if (c > 78) continue;
      float x = img[row*80 + c];
      float E = __expf(x * (4.0f/255.0f) - 2.0f);
      float t = 1.0f - 2.0f*__builtin_amdgcn_rcpf(E + 1.0f);
      float z = t - 1.0f;
      float e = ENC_NORM * __expf(-GC_C*z*z);
      float rg = __expf(-GC_2CD*z - GC_CD2);
      unsigned int pk[16];
      #pragma unroll
      for (int cp = 0; cp < 10; ++cp) {
        float e1 = e * rg;
        pk[cp] = pack_bf2(e, e1);
        e  = e1 * rg * GC_S1;
        rg = rg * S2;
      }
      #pragma unroll
      for (int cp = 10; cp < 16; ++cp) pk[cp] = 0u;
      unsigned short* dst = &ench[row][hx][0];
      *(uint4*)(dst)      = *(uint4*)&pk[0];
      *(uint4*)(dst + 8)  = *(uint4*)&pk[4];
      *(uint4*)(dst + 16) = *(uint4*)&pk[8];
      *(uint4*)(dst + 24) = *(uint4*)&pk[12];
    }
    barrier_lgkm();

    int totpx = 3 * OWH;
    {
      int t = wid;
      int pa = t*16 + lr;
      int pc = (pa < totpx) ? pa : (totpx - 1);
      int ohl = pc / OWH, lw = pc % OWH;
      f32x4 acc0 = {0.f,0.f,0.f,0.f}, acc1 = {0.f,0.f,0.f,0.f};
      #pragma unroll
      for (int kh = 0; kh < 3; ++kh) {
        int r = ohl*2 + kh;
        #pragma unroll
        for (int kw = 0; kw < 3; ++kw) {
          int hidx = (kw == 1) ? (21 + lw) : (lw + (kw >> 1));
          bf16x8 a = *(const bf16x8*)&ench[r][hidx][kg*8];
          int tap = kh*3 + kw;
          acc0 = __builtin_amdgcn_mfma_f32_16x16x32_bf16(a, bf0[tap], acc0, 0, 0, 0);
          acc1 = __builtin_amdgcn_mfma_f32_16x16x32_bf16(a, bf1[tap], acc1, 0, 0, 0);
        }
      }
      #pragma unroll
      for (int rr = 0; rr < 4; ++rr) {
        int ps = t*16 + kg*4 + rr;
        if (ps < totpx) {
          int soh = orow0 + ps / OWH, sow = owbase + ps % OWH;
          unsigned short* op = y + (((size_t)n*39 + soh)*39 + sow)*32;
          *(unsigned int*)(op + 2*lr) =
            pack_bf2(lrelu(acc0[rr] + b0), lrelu(acc1[rr] + b1));
        }
      }
    }
    barrier_lgkm();
  }
}

// ---------------- conv2: bf16 MFMA implicit GEMM, slab loop ----------------
template<int H, int W, int OH, int OW, int ROWS, int SLABS>
__global__ __launch_bounds__(256, 1) void k_cmfma(
    const unsigned short* __restrict__ in, const unsigned short* __restrict__ wc,
    const float* __restrict__ bias, unsigned short* __restrict__ out)
{
  constexpr int IR = 2*ROWS + 1;
  constexpr int EV = (W + 1) / 2;
  __shared__ unsigned short xs[IR][W][40];
  int n = blockIdx.x;
  int tid = threadIdx.x;
  int lane = tid & 63, wid = tid >> 6;
  int lr = lane & 15, kg = lane >> 4;

  bf16x8 bf0[9], bf1[9];
  #pragma unroll
  for (int tap = 0; tap < 9; ++tap) {
    bf0[tap] = *(const bf16x8*)&wc[(tap*32 + lr)*32      + kg*8];
    bf1[tap] = *(const bf16x8*)&wc[(tap*32 + 16 + lr)*32 + kg*8];
  }
  float b0 = bias[lr], b1 = bias[16 + lr];

  for (int s = 0; s < SLABS; ++s) {
    int orow0 = (blockIdx.y * SLABS + s) * ROWS;
    if (orow0 >= OH) break;
    int nrows = min(ROWS, OH - orow0);
    int irow0 = orow0 * 2;
    int ir = min(2*nrows + 1, H - irow0);

    const unsigned short* ip = in + ((size_t)n*H + irow0)*W*32;
    int npx = ir * W;
    for (int p = tid; p < npx; p += 256) {
      const uint4* src = (const uint4*)(ip + (size_t)p*32);
      uint4 v0 = src[0], v1 = src[1], v2 = src[2], v3 = src[3];
      int r = p / W, col = p % W;
      int hx = (col & 1) ? EV + (col >> 1) : (col >> 1);
      unsigned short* dst = &xs[r][hx][0];
      *(uint4*)(dst)      = v0;
      *(uint4*)(dst + 8)  = v1;
      *(uint4*)(dst + 16) = v2;
      *(uint4*)(dst + 24) = v3;
    }
    barrier_lgkm();

    int totpx = nrows * OW;
    int ntiles = (totpx + 15) >> 4;
    for (int t = wid; t < ntiles; t += 4) {
      int pa = t*16 + lr;
      int pc = (pa < totpx) ? pa : 0;
      int oh = pc / OW, ow = pc % OW;
      f32x4 acc0 = {0.f,0.f,0.f,0.f}, acc1 = {0.f,0.f,0.f,0.f};
      #pragma unroll
      for (int kh = 0; kh < 3; ++kh)
        #pragma unroll
        for (int kw = 0; kw < 3; ++kw) {
          int hidx = (kw == 1) ? (EV + ow) : (ow + (kw >> 1));
          bf16x8 a = *(const bf16x8*)&xs[oh*2 + kh][hidx][kg*8];
          acc0 = __builtin_amdgcn_mfma_f32_16x16x32_bf16(a, bf0[kh*3+kw], acc0, 0, 0, 0);
          acc1 = __builtin_amdgcn_mfma_f32_16x16x32_bf16(a, bf1[kh*3+kw], acc1, 0, 0, 0);
        }
      #pragma unroll
      for (int rr = 0; rr < 4; ++rr) {
        int ps = t*16 + kg*4 + rr;
        if (ps < totpx) {
          int soh = orow0 + ps / OW, sow = ps % OW;
          unsigned short* op = out + (((size_t)n*OH + soh)*OW + sow)*32;
          *(unsigned int*)(op + 2*lr) =
            pack_bf2(lrelu(acc0[rr] + b0), lrelu(acc1[rr] + b1));
        }
      }
    }
    barrier_lgkm();
  }
}

// ---------------- fused conv3+conv4 (per image) ----------------
__global__ __launch_bounds__(256, 1) void k_conv34(
    const unsigned short* __restrict__ in,
    const unsigned short* __restrict__ wc3, const float* __restrict__ b3,
    const unsigned short* __restrict__ wc4, const float* __restrict__ b4,
    unsigned short* __restrict__ out)
{
  __shared__ unsigned short xs[19][19][40];
  __shared__ unsigned short ys[9][9][40];
  int n = blockIdx.x;
  int tid = threadIdx.x;
  int lane = tid & 63, wid = tid >> 6;
  int lr = lane & 15, kg = lane >> 4;

  bf16x8 c3a[9], c3b[9], c4a[9], c4b[9];
  #pragma unroll
  for (int tap = 0; tap < 9; ++tap) {
    c3a[tap] = *(const bf16x8*)&wc3[(tap*32 + lr)*32      + kg*8];
    c3b[tap] = *(const bf16x8*)&wc3[(tap*32 + 16 + lr)*32 + kg*8];
    c4a[tap] = *(const bf16x8*)&wc4[(tap*32 + lr)*32      + kg*8];
    c4b[tap] = *(const bf16x8*)&wc4[(tap*32 + 16 + lr)*32 + kg*8];
  }
  float b30 = b3[lr], b31 = b3[16+lr];
  float b40 = b4[lr], b41 = b4[16+lr];

  const unsigned short* ip = in + (size_t)n*19*19*32;
  for (int p = tid; p < 361; p += 256) {
    const uint4* src = (const uint4*)(ip + (size_t)p*32);
    uint4 v0 = src[0], v1 = src[1], v2 = src[2], v3 = src[3];
    int r = p / 19, col = p % 19;
    int hx = (col & 1) ? 10 + (col >> 1) : (col >> 1);
    unsigned short* dst = &xs[r][hx][0];
    *(uint4*)(dst)      = v0;
    *(uint4*)(dst + 8)  = v1;
    *(uint4*)(dst + 16) = v2;
    *(uint4*)(dst + 24) = v3;
  }
  barrier_lgkm();

  for (int t = wid; t < 6; t += 4) {
    int pa = t*16 + lr;
    int pc = (pa < 81) ? pa : 0;
    int oh = pc / 9, ow = pc % 9;
    f32x4 acc0 = {0.f,0.f,0.f,0.f}, acc1 = {0.f,0.f,0.f,0.f};
    #pragma unroll
    for (int kh = 0; kh < 3; ++kh)
      #pragma unroll
      for (int kw = 0; kw < 3; ++kw) {
        int hidx = (kw == 1) ? (10 + ow) : (ow + (kw >> 1));
        bf16x8 a = *(const bf16x8*)&xs[oh*2 + kh][hidx][kg*8];
        acc0 = __builtin_amdgcn_mfma_f32_16x16x32_bf16(a, c3a[kh*3+kw], acc0, 0, 0, 0);
        acc1 = __builtin_amdgcn_mfma_f32_16x16x32_bf16(a, c3b[kh*3+kw], acc1, 0, 0, 0);
      }
    #pragma unroll
    for (int rr = 0; rr < 4; ++rr) {
      int ps = t*16 + kg*4 + rr;
      if (ps < 81) {
        int soh = ps / 9, sow = ps % 9;
        int hx2 = (sow & 1) ? 5 + (sow >> 1) : (sow >> 1);
        *(unsigned int*)&ys[soh][hx2][2*lr] =
          pack_bf2(lrelu(acc0[rr] + b30), lrelu(acc1[rr] + b31));
      }
    }
  }
  barrier_lgkm();

  if (wid == 0) {
    int pc = lr;
    int oh = pc >> 2, ow = pc & 3;
    f32x4 acc0 = {0.f,0.f,0.f,0.f}, acc1 = {0.f,0.f,0.f,0.f};
    #pragma unroll
    for (int kh = 0; kh < 3; ++kh)
      #pragma unroll
      for (int kw = 0; kw < 3; ++kw) {
        int hidx = (kw == 1) ? (5 + ow) : (ow + (kw >> 1));
        bf16x8 a = *(const bf16x8*)&ys[oh*2 + kh][hidx][kg*8];
        acc0 = __builtin_amdgcn_mfma_f32_16x16x32_bf16(a, c4a[kh*3+kw], acc0, 0, 0, 0);
        acc1 = __builtin_amdgcn_mfma_f32_16x16x32_bf16(a, c4b[kh*3+kw], acc1, 0, 0, 0);
      }
    #pragma unroll
    for (int rr = 0; rr < 4; ++rr) {
      int ps = kg*4 + rr;
      int soh = ps >> 2, sow = ps & 3;
      unsigned short* op = out + (((size_t)n*4 + soh)*4 + sow)*32;
      *(unsigned int*)(op + 2*lr) =
        pack_bf2(lrelu(acc0[rr] + b40), lrelu(acc1[rr] + b41));
    }
  }
}

// ---------------- bf16 MFMA GEMM via global_load_lds + XOR-swizzled LDS ----------------
template<int OUT_BF16, int ACT>
__global__ __launch_bounds__(256) void k_mgemm(
    const unsigned short* __restrict__ A, const unsigned short* __restrict__ Wt,
    const float* __restrict__ bias, void* __restrict__ Cv,
    int M, int N, int K)
{
  __shared__ unsigned short As[128*64];
  __shared__ unsigned short Bs[128*64];
  int bm = blockIdx.x * 128;
  int bn = blockIdx.y * 128;
  int tid = threadIdx.x;
  int wid = tid >> 6, lane = tid & 63;
  int wr = (wid >> 1) * 64, wc = (wid & 1) * 64;
  int lr = lane & 15, kg = lane >> 4;

  int srow = lane >> 3;
  int ssw  = ((lane & 7) * 16) ^ (srow << 4);
  int rsw  = (lr & 7) << 4;

  f32x4 acc[4][4];
  #pragma unroll
  for (int i = 0; i < 4; ++i)
    #pragma unroll
    for (int j = 0; j < 4; ++j)
      acc[i][j] = (f32x4){0.f,0.f,0.f,0.f};

  for (int k0 = 0; k0 < K; k0 += 64) {
    #pragma unroll
    for (int i = 0; i < 4; ++i) {
      int rowc = wid*32 + i*8;
      int row  = rowc + srow;
      gload16((const char*)&A[(size_t)(bm + row)*K + k0] + ssw, &As[rowc*64]);
      gload16((const char*)&Wt[(size_t)(bn + row)*K + k0] + ssw, &Bs[rowc*64]);
    }
    __syncthreads();
    #pragma unroll
    for (int ks = 0; ks < 2; ++ks) {
      int roff = ((ks*64 + kg*16) ^ rsw) >> 1;
      bf16x8 a[4], b[4];
      #pragma unroll
      for (int i = 0; i < 4; ++i) {
        a[i] = *(const bf16x8*)&As[(wr + i*16 + lr)*64 + roff];
        b[i] = *(const bf16x8*)&Bs[(wc + i*16 + lr)*64 + roff];
      }
      #pragma unroll
      for (int i = 0; i < 4; ++i)
        #pragma unroll
        for (int j = 0; j < 4; ++j)
          acc[i][j] = __builtin_amdgcn_mfma_f32_16x16x32_bf16(a[i], b[j], acc[i][j], 0, 0, 0);
    }
    __syncthreads();
  }
  int r0 = (lane >> 4) * 4;
  #pragma unroll
  for (int i = 0; i < 4; ++i) {
    #pragma unroll
    for (int j = 0; j < 4; ++j) {
      int col = bn + wc + j*16 + lr;
      float bv = bias ? bias[col] : 0.f;
      #pragma unroll
      for (int rr = 0; rr < 4; ++rr) {
        int row = bm + wr + i*16 + r0 + rr;
        float v = acc[i][j][rr] + bv;
        if (ACT) v = lrelu(v);
        if (OUT_BF16) ((unsigned short*)Cv)[(size_t)row*N + col] = f2bf(v);
        else          ((float*)Cv)[(size_t)row*N + col] = v;
      }
    }
  }
}

// ---------------- pair GEMM: fused expand + GEMM ----------------
__global__ __launch_bounds__(256) void k_pgemm(
    const unsigned short* __restrict__ UV, const unsigned short* __restrict__ Wt,
    const float* __restrict__ abias, const float* __restrict__ obias,
    unsigned short* __restrict__ C, int M, int N, int K)
{
  __shared__ unsigned short As[128*64];
  __shared__ unsigned short Bs[128*64];
  __shared__ float absm[512];
  int bm = blockIdx.x * 128;
  int bn = blockIdx.y * 128;
  int tid = threadIdx.x;
  int wid = tid >> 6, lane = tid & 63;
  int wr = (wid >> 1) * 64, wc = (wid & 1) * 64;
  int lr = lane & 15, kg = lane >> 4;
  int ld = 2*K;

  int srow = lane >> 3;
  int ssw  = ((lane & 7) * 16) ^ (srow << 4);
  int rsw  = (lr & 7) << 4;

  for (int idx = tid; idx < K; idx += 256) absm[idx] = abias[idx];

  int urow[4], vrow[4], arow[4], asw[4];
  #pragma unroll
  for (int i = 0; i < 4; ++i) {
    int ch = tid + (i << 8);
    int r = ch >> 3;
    int m = bm + r;
    int n = m / 81; int rem = m - n*81;
    int ii = rem / 9; int jj = rem - ii*9;
    urow[i] = n*9 + ii; vrow[i] = n*9 + jj;
    arow[i] = r;
    asw[i] = (((ch & 7) * 16) ^ ((r & 7) << 4)) >> 1;
  }
  __syncthreads();

  f32x4 acc[4][4];
  #pragma unroll
  for (int i = 0; i < 4; ++i)
    #pragma unroll
    for (int j = 0; j < 4; ++j)
      acc[i][j] = (f32x4){0.f,0.f,0.f,0.f};

  for (int k0 = 0; k0 < K; k0 += 64) {
    #pragma unroll
    for (int i = 0; i < 4; ++i) {
      int rowc = wid*32 + i*8;
      int row  = rowc + srow;
      gload16((const char*)&Wt[(size_t)(bn + row)*K + k0] + ssw, &Bs[rowc*64]);
    }
    #pragma unroll
    for (int i = 0; i < 4; ++i) {
      int ch = tid + (i << 8);
      int kc = (ch & 7) * 8;
      uint4 u4 = *(const uint4*)&UV[(size_t)urow[i]*ld + k0 + kc];
      uint4 v4 = *(const uint4*)&UV[(size_t)vrow[i]*ld + K + k0 + kc];
      const unsigned short* us = (const unsigned short*)&u4;
      const unsigned short* vs = (const unsigned short*)&v4;
      unsigned int pk[4];
      #pragma unroll
      for (int e2 = 0; e2 < 4; ++e2) {
        float a0 = bf2f(us[2*e2])   + bf2f(vs[2*e2])   + absm[k0 + kc + 2*e2];
        float a1 = bf2f(us[2*e2+1]) + bf2f(vs[2*e2+1]) + absm[k0 + kc + 2*e2+1];
        pk[e2] = pack_bf2(lrelu(a0), lrelu(a1));
      }
      *(uint4*)&As[arow[i]*64 + asw[i]] = *(uint4*)pk;
    }
    __syncthreads();
    #pragma unroll
    for (int ks = 0; ks < 2; ++ks) {
      int roff = ((ks*64 + kg*16) ^ rsw) >> 1;
      bf16x8 a[4], b[4];
      #pragma unroll
      for (int i = 0; i < 4; ++i) {
        a[i] = *(const bf16x8*)&As[(wr + i*16 + lr)*64 + roff];
        b[i] = *(const bf16x8*)&Bs[(wc + i*16 + lr)*64 + roff];
      }
      #pragma unroll
      for (int i = 0; i < 4; ++i)
        #pragma unroll
        for (int j = 0; j < 4; ++j)
          acc[i][j] = __builtin_amdgcn_mfma_f32_16x16x32_bf16(a[i], b[j], acc[i][j], 0, 0, 0);
    }
    __syncthreads();
  }
  int r0 = (lane >> 4) * 4;
  #pragma unroll
  for (int i = 0; i < 4; ++i) {
    #pragma unroll
    for (int j = 0; j < 4; ++j) {
      int col = bn + wc + j*16 + lr;
      float bv = obias[col];
      #pragma unroll
      for (int rr = 0; rr < 4; ++rr) {
        int row = bm + wr + i*16 + r0 + rr;
        C[(size_t)row*N + col] = f2bf(lrelu(acc[i][j][rr] + bv));
      }
    }
  }
}

// ---------------- g1 GEMM with objects built on the fly ----------------
__global__ __launch_bounds__(256) void k_g1o(
    const float* __restrict__ panel, const float* __restrict__ post_b,
    const unsigned short* __restrict__ Wt, unsigned short* __restrict__ C,
    int M, int N, int K)
{
  __shared__ unsigned short As[128*64];
  __shared__ unsigned short Bs[128*64];
  __shared__ float pbs[256];
  int bm = blockIdx.x * 128;
  int bn = blockIdx.y * 128;
  int tid = threadIdx.x;
  int wid = tid >> 6, lane = tid & 63;
  int wr = (wid >> 1) * 64, wc = (wid & 1) * 64;
  int lr = lane & 15, kg = lane >> 4;

  int srow = lane >> 3;
  int ssw  = ((lane & 7) * 16) ^ (srow << 4);
  int rsw  = (lr & 7) << 4;

  if (tid < 256) pbs[tid] = (tid < 247) ? post_b[tid] : 0.f;

  int srcr[4], slotr[4], arow[4], asw[4];
  #pragma unroll
  for (int i = 0; i < 4; ++i) {
    int ch = tid + (i << 8);
    int r = ch >> 3;
    int m = bm + r;
    int nn = m / 9; int sl = m - nn*9;
    int b = nn >> 3, opt = nn & 7;
    srcr[i] = (sl < 8) ? (b*16 + sl) : (b*16 + 8 + opt);
    slotr[i] = sl;
    arow[i] = r;
    asw[i] = (((ch & 7) * 16) ^ ((r & 7) << 4)) >> 1;
  }
  __syncthreads();

  f32x4 acc[4][4];
  #pragma unroll
  for (int i = 0; i < 4; ++i)
    #pragma unroll
    for (int j = 0; j < 4; ++j)
      acc[i][j] = (f32x4){0.f,0.f,0.f,0.f};

  for (int k0 = 0; k0 < K; k0 += 64) {
    #pragma unroll
    for (int i = 0; i < 4; ++i) {
      int rowc = wid*32 + i*8;
      int row  = rowc + srow;
      gload16((const char*)&Wt[(size_t)(bn + row)*K + k0] + ssw, &Bs[rowc*64]);
    }
    #pragma unroll
    for (int i = 0; i < 4; ++i) {
      int ch = tid + (i << 8);
      int kc = (ch & 7) * 8;
      int kb = k0 + kc;
      const float* pp = &panel[(size_t)srcr[i]*256 + kb];
      unsigned int pk[4];
      #pragma unroll
      for (int e2 = 0; e2 < 4; ++e2) {
        float v0 = pp[2*e2]   + pbs[kb + 2*e2];
        float v1 = pp[2*e2+1] + pbs[kb + 2*e2+1];
        int kk0 = kb + 2*e2, kk1 = kb + 2*e2 + 1;
        if (kk0 >= 247) v0 = (kk0 - 247 == slotr[i]) ? 1.f : 0.f;
        if (kk1 >= 247) v1 = (kk1 - 247 == slotr[i]) ? 1.f : 0.f;
        pk[e2] = pack_bf2(v0, v1);
      }
      *(uint4*)&As[arow[i]*64 + asw[i]] = *(uint4*)pk;
    }
    __syncthreads();
    #pragma unroll
    for (int ks = 0; ks < 2; ++ks) {
      int roff = ((ks*64 + kg*16) ^ rsw) >> 1;
      bf16x8 a[4], b[4];
      #pragma unroll
      for (int i = 0; i < 4; ++i) {
        a[i] = *(const bf16x8*)&As[(wr + i*16 + lr)*64 + roff];
        b[i] = *(const bf16x8*)&Bs[(wc + i*16 + lr)*64 + roff];
      }
      #pragma unroll
      for (int i = 0; i < 4; ++i)
        #pragma unroll
        for (int j = 0; j < 4; ++j)
          acc[i][j] = __builtin_amdgcn_mfma_f32_16x16x32_bf16(a[i], b[j], acc[i][j], 0, 0, 0);
    }
    __syncthreads();
  }
  int r0 = (lane >> 4) * 4;
  #pragma unroll
  for (int i = 0; i < 4; ++i) {
    #pragma unroll
    for (int j = 0; j < 4; ++j) {
      int col = bn + wc + j*16 + lr;
      #pragma unroll
      for (int rr = 0; rr < 4; ++rr) {
        int row = bm + wr + i*16 + r0 + rr;
        C[(size_t)row*N + col] = f2bf(acc[i][j][rr]);
      }
    }
  }
}

// ---------------- sum over j (vectorized x8); WSJ: write fp32, WSJB: write bf16 ----------------
template<int WSJ, int WSJB>
__global__ void k_sumj(const unsigned short* __restrict__ Z, float* __restrict__ SJ,
                       unsigned short* __restrict__ SJb, int C)
{
  int idx = blockIdx.x*256 + threadIdx.x;
  int vpr = C >> 3;
  int orow = idx / vpr, kv = (idx - orow*vpr) << 3;
  int n = orow / 9, i = orow % 9;
  const unsigned short* base = Z + (size_t)(n*81 + i*9)*C + kv;
  float s[8];
  #pragma unroll
  for (int e = 0; e < 8; ++e) s[e] = 0.f;
  #pragma unroll
  for (int j = 0; j < 9; ++j) {
    bf16x8 v = *(const bf16x8*)(base + (size_t)j*C);
    #pragma unroll
    for (int e = 0; e < 8; ++e) s[e] += bf2f(((const unsigned short*)&v)[e]);
  }
  if (WSJ) {
    float* so = SJ + (size_t)orow*C + kv;
    #pragma unroll
    for (int e = 0; e < 8; ++e) so[e] = s[e];
  }
  if (WSJB) {
    unsigned int pk[4];
    #pragma unroll
    for (int e2 = 0; e2 < 4; ++e2) pk[e2] = pack_bf2(s[2*e2], s[2*e2+1]);
    *(uint4*)(SJb + (size_t)orow*C + kv) = *(uint4*)pk;
  }
}

// ---------------- sum over i (vectorized x4) ----------------
__global__ void k_hsum(const float* __restrict__ SJ, float* __restrict__ HS,
                       unsigned short* __restrict__ HSb)
{
  int idx = blockIdx.x*256 + threadIdx.x;
  int n = idx >> 6, kc = (idx & 63) << 2;
  const float* base = SJ + (size_t)n*9*256 + kc;
  float4 s = {0.f,0.f,0.f,0.f};
  #pragma unroll
  for (int i = 0; i < 9; ++i) {
    float4 v = *(const float4*)(base + (size_t)i*256);
    s.x += v.x; s.y += v.y; s.z += v.z; s.w += v.w;
  }
  *(float4*)(HS + (size_t)n*256 + kc) = s;
  unsigned int pk[2];
  pk[0] = pack_bf2(s.x, s.y);
  pk[1] = pack_bf2(s.z, s.w);
  *(uint2*)(HSb + (size_t)n*256 + kc) = *(uint2*)pk;
}

// ---------------- fused tail ----------------
__global__ __launch_bounds__(256) void k_tailfin(
    const float* __restrict__ HS, const unsigned short* __restrict__ F2,
    const float* __restrict__ ffw, const float* __restrict__ ffb,
    float* __restrict__ out)
{
  __shared__ float red[256];
  __shared__ float wsm[256];
  int tid = threadIdx.x;
  wsm[tid] = ffw[tid];
  float s = 0.f;
  for (int j = 0; j < 256; ++j) { float v = HS[j*256 + tid]; s += v*v; }
  red[tid] = s; __syncthreads();
  for (int off = 128; off > 0; off >>= 1) { if (tid < off) red[tid] += red[tid + off]; __syncthreads(); }
  float hsq = red[0];
  __syncthreads();
  float r = ffb[0];
  for (int k = 0; k < 256; ++k) r += bf2f(F2[(size_t)tid*256 + k])*wsm[k];
  red[tid] = r*r; __syncthreads();
  for (int off = 128; off > 0; off >>= 1) { if (tid < off) red[tid] += red[tid + off]; __syncthreads(); }
  out[tid] = r;
  if (tid == 0) out[256] = hsq/65536.0f + red[0]/256.0f;
}

extern "C" void kernel_launch(void* const* d_in, const int* in_sizes, int n_in,
                              void* d_out, int out_size, void* d_ws, size_t ws_size,
                              hipStream_t stream)
{
  const float* batch   = (const float*)d_in[0];
  const float* conv_w1 = (const float*)d_in[1];
  const float* conv_b1 = (const float*)d_in[2];
  const float* conv_w2 = (const float*)d_in[3];
  const float* conv_b2 = (const float*)d_in[4];
  const float* conv_w3 = (const float*)d_in[5];
  const float* conv_b3 = (const float*)d_in[6];
  const float* conv_w4 = (const float*)d_in[7];
  const float* conv_b4 = (const float*)d_in[8];
  const float* post_w  = (const float*)d_in[9];
  const float* post_b  = (const float*)d_in[10];
  const float* g_w1    = (const float*)d_in[11];
  const float* g_b1    = (const float*)d_in[12];
  const float* g_w2    = (const float*)d_in[13];
  const float* g_b2    = (const float*)d_in[14];
  const float* g_w3    = (const float*)d_in[15];
  const float* g_b3    = (const float*)d_in[16];
  const float* g_w4    = (const float*)d_in[17];
  const float* g_b4    = (const float*)d_in[18];
  const float* h_w1    = (const float*)d_in[19];
  const float* h_b1    = (const float*)d_in[20];
  const float* h_w2    = (const float*)d_in[21];
  const float* h_b2    = (const float*)d_in[22];
  const float* h_w3    = (const float*)d_in[23];
  const float* h_b3    = (const float*)d_in[24];
  const float* f_w1    = (const float*)d_in[25];
  const float* f_b1    = (const float*)d_in[26];
  const float* f_w2    = (const float*)d_in[27];
  const float* f_b2    = (const float*)d_in[28];
  const float* ff_w    = (const float*)d_in[29];
  const float* ff_b    = (const float*)d_in[30];

  char* wsb = (char*)d_ws;
  const size_t off_Y1    = 0;
  const size_t off_Y2    = 52000000;
  const size_t off_Y4    = 67000000;
  const size_t off_PANEL = 68000000;
  const size_t off_WT    = 132000000;
  const size_t off_Pb    = 0;
  const size_t off_Qb    = 22000000;
  const size_t off_UV    = 44000000;
  const size_t off_SJ    = 56000000;
  const size_t off_SJb   = 59000000;
  const size_t off_HS    = 61000000;
  const size_t off_HSb   = 61500000;
  const size_t off_F1    = 62000000;
  const size_t off_F2    = 63000000;

  unsigned short* WT = (unsigned short*)(wsb + off_WT);
  const size_t wt_g1   = 0;
  const size_t wt_g2   = 262144;
  const size_t wt_g3   = 524288;
  const size_t wt_g4   = 786432;
  const size_t wt_h1   = 917504;
  const size_t wt_h2   = 1310720;
  const size_t wt_h3   = 1507328;
  const size_t wt_post = 1703936;
  const size_t wt_cw2  = 1835008;
  const size_t wt_cw3  = 1844224;
  const size_t wt_cw4  = 1853440;
  const size_t wt_cw1  = 1862656;
  const size_t wt_f1   = 1871872;
  const size_t wt_f2   = 1937408;

  dim3 b256(256);

  k_prep<<<dim3(7824), b256, 0, stream>>>(g_w1, g_w2, g_w3, g_w4, h_w1, h_w2, h_w3,
                                          post_w, conv_w2, conv_w3, conv_w4, conv_w1,
                                          f_w1, f_w2, WT);

  unsigned short* Y1 = (unsigned short*)(wsb + off_Y1);
  unsigned short* Y2 = (unsigned short*)(wsb + off_Y2);
  unsigned short* Y4 = (unsigned short*)(wsb + off_Y4);
  float* PANEL = (float*)(wsb + off_PANEL);

  k_conv1m<<<dim3(512,2,2), b256, 0, stream>>>(batch, WT + wt_cw1, conv_b1, Y1);
  k_cmfma<39,39,19,19,5,2><<<dim3(512,2), b256, 0, stream>>>(Y1, WT + wt_cw2, conv_b2, Y2);
  k_conv34<<<dim3(512), b256, 0, stream>>>(Y2, WT + wt_cw3, conv_b3, WT + wt_cw4, conv_b4, Y4);

  k_mgemm<0,0><<<dim3(4,2), b256, 0, stream>>>(Y4, WT + wt_post, nullptr, PANEL, 512,256,512);

  unsigned short* Pb  = (unsigned short*)(wsb + off_Pb);
  unsigned short* Qb  = (unsigned short*)(wsb + off_Qb);
  unsigned short* UVb = (unsigned short*)(wsb + off_UV);
  unsigned short* SJb = (unsigned short*)(wsb + off_SJb);
  float* SJ = (float*)(wsb + off_SJ);
  float* HS = (float*)(wsb + off_HS);
  unsigned short* HSb = (unsigned short*)(wsb + off_HSb);
  unsigned short* F1 = (unsigned short*)(wsb + off_F1);
  unsigned short* F2 = (unsigned short*)(wsb + off_F2);

  // g-MLP (objects folded into g1 staging)
  k_g1o<<<dim3(18,8), b256, 0, stream>>>(PANEL, post_b, WT + wt_g1, UVb, 2304,1024,256);
  k_pgemm<<<dim3(162,4), b256, 0, stream>>>(UVb, WT + wt_g2, g_b1, g_b2, Qb, 20736,512,512);
  k_mgemm<1,1><<<dim3(162,4), b256, 0, stream>>>(Qb, WT + wt_g3, g_b3, Pb, 20736,512,512);
  k_mgemm<1,1><<<dim3(162,2), b256, 0, stream>>>(Pb, WT + wt_g4, g_b4, Qb, 20736,256,512);
  k_sumj<0,1><<<dim3(288), b256, 0, stream>>>(Qb, SJ, SJb, 256);

  // h loop
  for (int i = 0; i < 3; ++i) {
    k_mgemm<1,0><<<dim3(18,4), b256, 0, stream>>>(SJb, WT + wt_h1 + (size_t)i*131072, nullptr, UVb, 2304,512,256);
    k_pgemm<<<dim3(162,2), b256, 0, stream>>>(UVb, WT + wt_h2 + (size_t)i*65536, h_b1 + i*256, h_b2 + i*256, Qb, 20736,256,256);
    k_mgemm<1,1><<<dim3(162,2), b256, 0, stream>>>(Qb, WT + wt_h3 + (size_t)i*65536, h_b3 + i*256, Pb, 20736,256,256);
    if (i < 2) k_sumj<0,1><<<dim3(288), b256, 0, stream>>>(Pb, SJ, SJb, 256);
    else       k_sumj<1,0><<<dim3(288), b256, 0, stream>>>(Pb, SJ, SJb, 256);
  }

  // head
  k_hsum<<<dim3(64), b256, 0, stream>>>(SJ, HS, HSb);
  k_mgemm<1,1><<<dim3(2,2), b256, 0, stream>>>(HSb, WT + wt_f1, f_b1, F1, 256,256,256);
  k_mgemm<1,1><<<dim3(2,2), b256, 0, stream>>>(F1,  WT + wt_f2, f_b2, F2, 256,256,256);
  k_tailfin<<<dim3(1), b256, 0, stream>>>(HS, F2, ff_w, ff_b, (float*)d_out);
}